// Round 2
// baseline (141.462 us; speedup 1.0000x reference)
//
#include <hip/hip_runtime.h>
#include <hip/hip_bf16.h>

// GCN layer, N=8192, E=262144, D=256.
// out = adj_norm @ (X @ W^T) + b   (rows of adj_norm sum to 1 -> bias commutes)
// adj = dedup'd edge set (bitmap) + I; deg = ndistinct + 1.
// GEMM in bf16 split-precision (3 MFMA passes), err ~2^-16 relative.

#define NNODES 8192
#define DFEAT  256
#define WORDS_PER_ROW (NNODES / 32)   // 256 u32 per bitmap row
#define MAXDEG 192                    // Poisson(32): P(deg>=192) ~ 1e-80

typedef __attribute__((ext_vector_type(8))) short   s16x8;
typedef __attribute__((ext_vector_type(4))) float   f32x4;

// ---- bf16 helpers (RNE) ----
__device__ inline unsigned short f2bf(float f) {
  unsigned u = __float_as_uint(f);
  return (unsigned short)((u + 0x7fffu + ((u >> 16) & 1u)) >> 16);
}
__device__ inline float bf2f(unsigned short h) {
  return __uint_as_float(((unsigned)h) << 16);
}

// -------- kernel 1: scatter edges -> bitmap dedup + CSR (deg, adj) --------
__global__ __launch_bounds__(256) void scatter_build(
    const int* __restrict__ ei, int E, unsigned* __restrict__ bitmap,
    int* __restrict__ deg, unsigned short* __restrict__ adj) {
  int e = blockIdx.x * 256 + threadIdx.x;
  if (e < E) {
    int s = ei[e];          // edge_index[0][e]
    int d = ei[E + e];      // edge_index[1][e]
    unsigned bit = 1u << (d & 31);
    unsigned old = atomicOr(&bitmap[(size_t)s * WORDS_PER_ROW + (d >> 5)], bit);
    if (!(old & bit)) {     // first setter appends (dedup)
      int pos = atomicAdd(&deg[s], 1);
      if (pos < MAXDEG) adj[(size_t)s * MAXDEG + pos] = (unsigned short)d;
    }
  }
}

// -------- kernel 2: split-convert X and W to (hi, lo) bf16 --------
__global__ __launch_bounds__(256) void convert_split(
    const float* __restrict__ X, const float* __restrict__ W,
    unsigned short* __restrict__ Xh, unsigned short* __restrict__ Xl,
    unsigned short* __restrict__ Wh, unsigned short* __restrict__ Wl) {
  const int NX = NNODES * DFEAT / 4;   // float4 chunks of X
  const int NW = DFEAT * DFEAT / 4;    // float4 chunks of W
  int i = blockIdx.x * 256 + threadIdx.x;
  const float* src; unsigned short* dh; unsigned short* dl; int j;
  if (i < NX)            { src = X; dh = Xh; dl = Xl; j = i; }
  else if (i < NX + NW)  { src = W; dh = Wh; dl = Wl; j = i - NX; }
  else return;
  float4 v = *(const float4*)(src + (size_t)j * 4);
  ushort4 h, l;
  h.x = f2bf(v.x); l.x = f2bf(v.x - bf2f(h.x));
  h.y = f2bf(v.y); l.y = f2bf(v.y - bf2f(h.y));
  h.z = f2bf(v.z); l.z = f2bf(v.z - bf2f(h.z));
  h.w = f2bf(v.w); l.w = f2bf(v.w - bf2f(h.w));
  *(ushort4*)(dh + (size_t)j * 4) = h;
  *(ushort4*)(dl + (size_t)j * 4) = l;
}

// -------- kernel 3: Y = X @ W^T via bf16 split MFMA --------
// block = 256 thr = 4 waves; block tile 64 rows x 64 cols; wave -> 16 rows.
// A frag: lane l reads X[row0 + (l&15)][k0 + (l>>4)*8 .. +8]  (16B contiguous)
// B frag: lane l reads W[col0 + (l&15)][k0 + (l>>4)*8 .. +8]  (Y[m][n]=sum X[m][k]W[n][k])
// C/D:    col = lane&15, row = (lane>>4)*4 + r   [m89-verified]
#define GBM 64
#define GBN 64
__global__ __launch_bounds__(256) void gemm_mfma(
    const unsigned short* __restrict__ Xh, const unsigned short* __restrict__ Xl,
    const unsigned short* __restrict__ Wh, const unsigned short* __restrict__ Wl,
    float* __restrict__ Y) {
  const int tid  = threadIdx.x;
  const int wave = tid >> 6;
  const int lane = tid & 63;
  const int row0 = blockIdx.x * GBM + wave * 16;
  const int col0 = blockIdx.y * GBN;
  const int lr = lane & 15;
  const int kh = (lane >> 4) * 8;

  f32x4 acc[4];
#pragma unroll
  for (int i = 0; i < 4; ++i) acc[i] = (f32x4){0.f, 0.f, 0.f, 0.f};

  const unsigned short* xph = Xh + (size_t)(row0 + lr) * DFEAT + kh;
  const unsigned short* xpl = Xl + (size_t)(row0 + lr) * DFEAT + kh;
  const unsigned short* wph = Wh + (size_t)(col0 + lr) * DFEAT + kh;
  const unsigned short* wpl = Wl + (size_t)(col0 + lr) * DFEAT + kh;

  for (int k0 = 0; k0 < DFEAT; k0 += 32) {
    s16x8 ah = *(const s16x8*)(xph + k0);
    s16x8 al = *(const s16x8*)(xpl + k0);
#pragma unroll
    for (int nt = 0; nt < 4; ++nt) {
      s16x8 bh = *(const s16x8*)(wph + k0 + nt * 16 * DFEAT);
      s16x8 bl = *(const s16x8*)(wpl + k0 + nt * 16 * DFEAT);
      acc[nt] = __builtin_amdgcn_mfma_f32_16x16x32_bf16(ah, bh, acc[nt], 0, 0, 0);
      acc[nt] = __builtin_amdgcn_mfma_f32_16x16x32_bf16(ah, bl, acc[nt], 0, 0, 0);
      acc[nt] = __builtin_amdgcn_mfma_f32_16x16x32_bf16(al, bh, acc[nt], 0, 0, 0);
    }
  }

  const int crow  = row0 + (lane >> 4) * 4;
  const int ccol  = col0 + (lane & 15);
#pragma unroll
  for (int nt = 0; nt < 4; ++nt)
#pragma unroll
    for (int r = 0; r < 4; ++r)
      Y[(size_t)(crow + r) * DFEAT + ccol + nt * 16] = acc[nt][r];
}

// -------- kernel 4: out[i] = (sum_nbr Y[j] + Y[i]) / (deg+1) + b --------
// 4 quarter-blocks per node (64 ch each): per-XCD L2 working set ~2MB.
__global__ __launch_bounds__(64) void aggregate(
    const int* __restrict__ deg, const unsigned short* __restrict__ adj,
    const float* __restrict__ Y, const float* __restrict__ bias,
    float* __restrict__ out) {
  const int b    = blockIdx.x;
  const int node = b >> 2;
  const int q    = b & 3;
  const int ch   = q * 64 + threadIdx.x;
  const int d    = deg[node];
  const unsigned short* lst = adj + (size_t)node * MAXDEG;

  float a0 = Y[(size_t)node * DFEAT + ch];  // +I self term
  float a1 = 0.f, a2 = 0.f, a3 = 0.f;
  int k = 0;
  for (; k + 4 <= d; k += 4) {
    int j0 = lst[k], j1 = lst[k + 1], j2 = lst[k + 2], j3 = lst[k + 3];
    a0 += Y[(size_t)j0 * DFEAT + ch];
    a1 += Y[(size_t)j1 * DFEAT + ch];
    a2 += Y[(size_t)j2 * DFEAT + ch];
    a3 += Y[(size_t)j3 * DFEAT + ch];
  }
  for (; k < d; ++k) a0 += Y[(size_t)lst[k] * DFEAT + ch];

  out[(size_t)node * DFEAT + ch] =
      (a0 + a1 + a2 + a3) / (float)(d + 1) + bias[ch];
}

extern "C" void kernel_launch(void* const* d_in, const int* in_sizes, int n_in,
                              void* d_out, int out_size, void* d_ws, size_t ws_size,
                              hipStream_t stream) {
  const float* x  = (const float*)d_in[0];
  const int*   ei = (const int*)d_in[1];
  const float* W  = (const float*)d_in[2];
  const float* b  = (const float*)d_in[3];
  float* out = (float*)d_out;
  const int E = in_sizes[1] / 2;

  // workspace layout (all 256B-aligned)
  char* p = (char*)d_ws;
  size_t off = 0;
  auto take = [&](size_t bytes) { char* r = p + off; off = (off + bytes + 255) & ~(size_t)255; return r; };
  unsigned*       bitmap = (unsigned*)       take((size_t)NNODES * WORDS_PER_ROW * 4); // 8 MB
  int*            degp   = (int*)            take((size_t)NNODES * 4);                 // 32 KB (contiguous after bitmap -> one memset)
  unsigned short* adj    = (unsigned short*) take((size_t)NNODES * MAXDEG * 2);        // 3 MB
  unsigned short* Xh     = (unsigned short*) take((size_t)NNODES * DFEAT * 2);
  unsigned short* Xl     = (unsigned short*) take((size_t)NNODES * DFEAT * 2);
  unsigned short* Wh     = (unsigned short*) take((size_t)DFEAT * DFEAT * 2);
  unsigned short* Wl     = (unsigned short*) take((size_t)DFEAT * DFEAT * 2);
  float*          Y      = (float*)          take((size_t)NNODES * DFEAT * 4);

  // zero bitmap + deg in one shot (they are adjacent)
  hipMemsetAsync(bitmap, 0, (size_t)NNODES * WORDS_PER_ROW * 4 + (size_t)NNODES * 4 + 256, stream);

  scatter_build<<<(E + 255) / 256, 256, 0, stream>>>(ei, E, bitmap, degp, adj);

  const int nconv = (NNODES * DFEAT / 4) + (DFEAT * DFEAT / 4);
  convert_split<<<(nconv + 255) / 256, 256, 0, stream>>>(x, W, Xh, Xl, Wh, Wl);

  gemm_mfma<<<dim3(NNODES / GBM, DFEAT / GBN), 256, 0, stream>>>(Xh, Xl, Wh, Wl, Y);

  aggregate<<<NNODES * 4, 64, 0, stream>>>(degp, adj, Y, b, out);
}

// Round 4
// 136.397 us; speedup vs baseline: 1.0371x; 1.0371x over previous
//
#include <hip/hip_runtime.h>
#include <hip/hip_bf16.h>
#include <hip/hip_fp16.h>

// GCN layer, N=8192, E=262144, D=256.
// out = adj_norm @ (X @ W^T) + b   (rows of adj_norm sum to 1 -> bias commutes)
// adj = dedup'd edge set (bitmap) + I; deg = ndistinct + 1.
// GEMM: fp16 2-pass split (Xh * (Wh + Wl)); only X-rounding error ~4e-4.
// Aggregate: channel-sliced so each XCD's Y working set (2MB) fits its L2.

#define NNODES 8192
#define DFEAT  256
#define WORDS_PER_ROW (NNODES / 32)   // 256 u32 per bitmap row
#define MAXDEG 192                    // Poisson(32): P(deg>=192) ~ 1e-80

typedef __attribute__((ext_vector_type(8))) _Float16 f16x8;
typedef __attribute__((ext_vector_type(4))) _Float16 f16x4;
typedef __attribute__((ext_vector_type(4))) float    f32x4;

// -------- kernel 1: scatter edges -> bitmap dedup + CSR (deg, adj) --------
__global__ __launch_bounds__(256) void gcn_scatter(
    const int* __restrict__ ei, int E, unsigned* __restrict__ bitmap,
    int* __restrict__ deg, unsigned short* __restrict__ adj) {
  int e = blockIdx.x * 256 + threadIdx.x;
  if (e < E) {
    int s = ei[e];          // edge_index[0][e]
    int d = ei[E + e];      // edge_index[1][e]
    unsigned bit = 1u << (d & 31);
    unsigned old = atomicOr(&bitmap[(size_t)s * WORDS_PER_ROW + (d >> 5)], bit);
    if (!(old & bit)) {     // first setter appends (dedup)
      int pos = atomicAdd(&deg[s], 1);
      if (pos < MAXDEG) adj[(size_t)s * MAXDEG + pos] = (unsigned short)d;
    }
  }
}

// -------- kernel 2: convert X -> fp16, W -> (Wh, Wl) fp16 pair --------
__global__ __launch_bounds__(256) void gcn_convert(
    const float* __restrict__ X, const float* __restrict__ W,
    _Float16* __restrict__ Xh, _Float16* __restrict__ Wh,
    _Float16* __restrict__ Wl) {
  const int NX = NNODES * DFEAT / 4;
  const int NW = DFEAT * DFEAT / 4;
  int i = blockIdx.x * 256 + threadIdx.x;
  if (i < NX) {
    float4 v = *(const float4*)(X + (size_t)i * 4);
    f16x4 h = {(_Float16)v.x, (_Float16)v.y, (_Float16)v.z, (_Float16)v.w};
    *(f16x4*)(Xh + (size_t)i * 4) = h;
  } else if (i < NX + NW) {
    int j = i - NX;
    float4 v = *(const float4*)(W + (size_t)j * 4);
    f16x4 h = {(_Float16)v.x, (_Float16)v.y, (_Float16)v.z, (_Float16)v.w};
    f16x4 l = {(_Float16)(v.x - (float)h[0]), (_Float16)(v.y - (float)h[1]),
               (_Float16)(v.z - (float)h[2]), (_Float16)(v.w - (float)h[3])};
    *(f16x4*)(Wh + (size_t)j * 4) = h;
    *(f16x4*)(Wl + (size_t)j * 4) = l;
  }
}

// -------- kernel 3: Y = Xh @ (Wh + Wl)^T via fp16 MFMA (2 passes) --------
// block = 4 waves; tile 64 rows x 64 cols; wave -> 16 rows x 64 cols.
// A frag: lane l reads Xh[row0 + (l&15)][k0 + (l>>4)*8 ..+8]
// B frag: lane l reads W*[col0 + nt*16 + (l&15)][k0 + (l>>4)*8 ..+8]
// C/D:    col = lane&15 (+nt*16), row = (lane>>4)*4 + r   [m89-verified]
__global__ __launch_bounds__(256) void gcn_gemm(
    const _Float16* __restrict__ Xh, const _Float16* __restrict__ Wh,
    const _Float16* __restrict__ Wl, float* __restrict__ Y) {
  const int tid  = threadIdx.x;
  const int wave = tid >> 6;
  const int lane = tid & 63;
  const int row0 = blockIdx.x * 64 + wave * 16;
  const int col0 = blockIdx.y * 64;
  const int lr = lane & 15;
  const int kh = (lane >> 4) * 8;

  f32x4 acc[4];
#pragma unroll
  for (int i = 0; i < 4; ++i) acc[i] = (f32x4){0.f, 0.f, 0.f, 0.f};

  const _Float16* ap  = Xh + (size_t)(row0 + lr) * DFEAT + kh;
  const _Float16* bhp = Wh + (size_t)(col0 + lr) * DFEAT + kh;
  const _Float16* blp = Wl + (size_t)(col0 + lr) * DFEAT + kh;

#pragma unroll
  for (int k0 = 0; k0 < DFEAT; k0 += 32) {
    f16x8 a = *(const f16x8*)(ap + k0);
#pragma unroll
    for (int nt = 0; nt < 4; ++nt) {
      f16x8 bh = *(const f16x8*)(bhp + k0 + nt * 16 * DFEAT);
      f16x8 bl = *(const f16x8*)(blp + k0 + nt * 16 * DFEAT);
      acc[nt] = __builtin_amdgcn_mfma_f32_16x16x32_f16(a, bh, acc[nt], 0, 0, 0);
      acc[nt] = __builtin_amdgcn_mfma_f32_16x16x32_f16(a, bl, acc[nt], 0, 0, 0);
    }
  }

  const int crow = row0 + (lane >> 4) * 4;
  const int ccol = col0 + (lane & 15);
#pragma unroll
  for (int nt = 0; nt < 4; ++nt)
#pragma unroll
    for (int r = 0; r < 4; ++r)
      Y[(size_t)(crow + r) * DFEAT + ccol + nt * 16] = acc[nt][r];
}

// -------- kernel 4: out[i] = (sum_nbr Y[j] + Y[i]) / (deg+1) + b --------
// Channel-sliced for XCD L2 residency: slice s = (blockIdx&7)>>1 covers
// channels [s*64, s*64+64); with round-robin block->XCD dispatch, each XCD
// only touches a 2MB Y-slice (fits 4MB L2). One wave = one node's slice.
// Grid = NNODES blocks (8192): for node-group g = 2k+p, blocks
// bI = 8k + {p, p+2, p+4, p+6} supply slices {0,1,2,3} — exact cover.
__global__ __launch_bounds__(256) void gcn_aggregate(
    const int* __restrict__ deg, const unsigned short* __restrict__ adj,
    const float* __restrict__ Y, const float* __restrict__ bias,
    float* __restrict__ out) {
  const int bI  = blockIdx.x;                    // 0..8191
  const int s   = (bI & 7) >> 1;                 // slice 0..3 (2 XCDs each)
  const int g   = ((bI >> 3) << 1) + (bI & 1);   // node-group 0..2047
  const int node = g * 4 + (threadIdx.x >> 6);   // 0..8191
  const int ch   = s * 64 + (threadIdx.x & 63);

  const int d  = deg[node];
  const int dc = min(d, MAXDEG);
  const unsigned short* lst = adj + (size_t)node * MAXDEG;

  float a0 = Y[(size_t)node * DFEAT + ch];  // +I self term
  float a1 = 0.f, a2 = 0.f, a3 = 0.f;
  int k = 0;
  for (; k + 4 <= dc; k += 4) {
    int j0 = lst[k], j1 = lst[k + 1], j2 = lst[k + 2], j3 = lst[k + 3];
    a0 += Y[(size_t)j0 * DFEAT + ch];
    a1 += Y[(size_t)j1 * DFEAT + ch];
    a2 += Y[(size_t)j2 * DFEAT + ch];
    a3 += Y[(size_t)j3 * DFEAT + ch];
  }
  for (; k < dc; ++k) a0 += Y[(size_t)lst[k] * DFEAT + ch];

  out[(size_t)node * DFEAT + ch] =
      (a0 + a1 + a2 + a3) / (float)(d + 1) + bias[ch];
}

extern "C" void kernel_launch(void* const* d_in, const int* in_sizes, int n_in,
                              void* d_out, int out_size, void* d_ws, size_t ws_size,
                              hipStream_t stream) {
  const float* x  = (const float*)d_in[0];
  const int*   ei = (const int*)d_in[1];
  const float* W  = (const float*)d_in[2];
  const float* b  = (const float*)d_in[3];
  float* out = (float*)d_out;
  const int E = in_sizes[1] / 2;

  // workspace layout (256B-aligned slices)
  char* p = (char*)d_ws;
  size_t off = 0;
  auto take = [&](size_t bytes) { char* r = p + off; off = (off + bytes + 255) & ~(size_t)255; return r; };
  unsigned*       bitmap = (unsigned*)       take((size_t)NNODES * WORDS_PER_ROW * 4); // 8 MB
  int*            degp   = (int*)            take((size_t)NNODES * 4);                 // 32 KB (adjacent -> one memset)
  unsigned short* adj    = (unsigned short*) take((size_t)NNODES * MAXDEG * 2);        // 3 MB
  _Float16*       Xh     = (_Float16*)       take((size_t)NNODES * DFEAT * 2);         // 4 MB
  _Float16*       Wh     = (_Float16*)       take((size_t)DFEAT * DFEAT * 2);
  _Float16*       Wl     = (_Float16*)       take((size_t)DFEAT * DFEAT * 2);
  float*          Y      = (float*)          take((size_t)NNODES * DFEAT * 4);         // 8 MB

  // zero bitmap + deg in one shot (adjacent)
  hipMemsetAsync(bitmap, 0, (size_t)NNODES * WORDS_PER_ROW * 4 + (size_t)NNODES * 4 + 256, stream);

  gcn_scatter<<<(E + 255) / 256, 256, 0, stream>>>(ei, E, bitmap, degp, adj);

  const int nconv = (NNODES * DFEAT / 4) + (DFEAT * DFEAT / 4);
  gcn_convert<<<(nconv + 255) / 256, 256, 0, stream>>>(x, W, Xh, Wh, Wl);

  gcn_gemm<<<dim3(NNODES / 64, DFEAT / 64), 256, 0, stream>>>(Xh, Wh, Wl, Y);

  gcn_aggregate<<<NNODES, 256, 0, stream>>>(degp, adj, Y, b, out);
}

// Round 7
// 121.576 us; speedup vs baseline: 1.1636x; 1.1219x over previous
//
#include <hip/hip_runtime.h>
#include <hip/hip_fp16.h>

// GCN layer, N=8192, E=262144, D=256.
// out = adj_norm @ (X @ W^T) + b   (rows of adj_norm sum to 1 -> bias commutes)
// adj = dedup'd edge set (bitmap) + I; deg = popcount(row) + 1.
// GEMM: fp16 2-pass split  Y = X16 @ (Wh + Wl)^T  (only X-rounding error ~5e-4),
//       X converted in-register (no staging pass). Y stored fp16:
//       4 MB total -> fits EVERY XCD's 4MB L2 regardless of block->XCD mapping.

#define NNODES 8192
#define DFEAT  256
#define WPR    256          // bitmap words per row
#define LISTCAP 2048        // max neighbors tracked (deg ~ Poisson(32); huge margin)

typedef __attribute__((ext_vector_type(8))) _Float16 f16x8;
typedef __attribute__((ext_vector_type(4))) _Float16 f16x4;
typedef __attribute__((ext_vector_type(4))) float    f32x4;

// ---- kernel 1: edge scatter (bitmap dedup) + W split-convert, fused ----
__global__ __launch_bounds__(256) void gcn_scatter_wconv(
    const int* __restrict__ ei, int E, unsigned* __restrict__ bitmap,
    const float* __restrict__ W, _Float16* __restrict__ Wh,
    _Float16* __restrict__ Wl) {
  const int nbs = (E + 255) >> 8;          // scatter blocks
  const int b = blockIdx.x;
  if (b < nbs) {
    int e = b * 256 + threadIdx.x;
    if (e < E) {
      int s = ei[e];                        // edge_index[0][e]
      int d = ei[E + e];                    // edge_index[1][e]
      atomicOr(&bitmap[(size_t)s * WPR + (d >> 5)], 1u << (d & 31));
    }
  } else {
    int i = (b - nbs) * 256 + threadIdx.x;  // float4 chunk over W (16384 total)
    if (i < DFEAT * DFEAT / 4) {
      float4 v = *(const float4*)(W + (size_t)i * 4);
      f16x4 h = {(_Float16)v.x, (_Float16)v.y, (_Float16)v.z, (_Float16)v.w};
      f16x4 l = {(_Float16)(v.x - (float)h[0]), (_Float16)(v.y - (float)h[1]),
                 (_Float16)(v.z - (float)h[2]), (_Float16)(v.w - (float)h[3])};
      *(f16x4*)(Wh + (size_t)i * 4) = h;
      *(f16x4*)(Wl + (size_t)i * 4) = l;
    }
  }
}

// ---- kernel 2: Y(fp16) = X @ (Wh + Wl)^T via fp16 MFMA, X cvt in-register ----
// block = 4 waves; tile 64 rows x 64 cols; wave -> 16 rows x 64 cols.
// A frag: lane l reads X[row0 + (l&15)][k0 + (l>>4)*8 ..+8] fp32 -> cvt fp16
// B frag: lane l reads W*[col0 + nt*16 + (l&15)][k0 + (l>>4)*8 ..+8]
// C/D:    col = lane&15 (+nt*16), row = (lane>>4)*4 + r   [m89-verified]
__global__ __launch_bounds__(256) void gcn_gemm(
    const float* __restrict__ X, const _Float16* __restrict__ Wh,
    const _Float16* __restrict__ Wl, _Float16* __restrict__ Y) {
  const int wave = threadIdx.x >> 6;
  const int lane = threadIdx.x & 63;
  const int row0 = blockIdx.x * 64 + wave * 16;
  const int col0 = blockIdx.y * 64;
  const int lr = lane & 15;
  const int kh = (lane >> 4) * 8;

  f32x4 acc[4];
#pragma unroll
  for (int i = 0; i < 4; ++i) acc[i] = (f32x4){0.f, 0.f, 0.f, 0.f};

  const float*    ap  = X  + (size_t)(row0 + lr) * DFEAT + kh;
  const _Float16* bhp = Wh + (size_t)(col0 + lr) * DFEAT + kh;
  const _Float16* blp = Wl + (size_t)(col0 + lr) * DFEAT + kh;

#pragma unroll
  for (int k0 = 0; k0 < DFEAT; k0 += 32) {
    float4 x0 = *(const float4*)(ap + k0);
    float4 x1 = *(const float4*)(ap + k0 + 4);
    f16x8 a = {(_Float16)x0.x, (_Float16)x0.y, (_Float16)x0.z, (_Float16)x0.w,
               (_Float16)x1.x, (_Float16)x1.y, (_Float16)x1.z, (_Float16)x1.w};
#pragma unroll
    for (int nt = 0; nt < 4; ++nt) {
      f16x8 bh = *(const f16x8*)(bhp + k0 + nt * 16 * DFEAT);
      f16x8 bl = *(const f16x8*)(blp + k0 + nt * 16 * DFEAT);
      acc[nt] = __builtin_amdgcn_mfma_f32_16x16x32_f16(a, bh, acc[nt], 0, 0, 0);
      acc[nt] = __builtin_amdgcn_mfma_f32_16x16x32_f16(a, bl, acc[nt], 0, 0, 0);
    }
  }

  const int crow = row0 + (lane >> 4) * 4;
  const int ccol = col0 + lr;
#pragma unroll
  for (int nt = 0; nt < 4; ++nt)
#pragma unroll
    for (int r = 0; r < 4; ++r)
      Y[(size_t)(crow + r) * DFEAT + ccol + nt * 16] = (_Float16)acc[nt][r];
}

// ---- kernel 3: out[i] = (sum_{j in row(i)} Y[j] + Y[i]) / (deg+1) + b ----
// One block per node; thread t = channel t. Bitmap row -> LDS list -> gather.
// Y is 4MB fp16: L2-resident on every XCD after warmup (no mapping assumption).
// Self-edge case: node appears in its own list -> Y[node] counted twice,
// matching reference's adj+I diagonal of 2.0; deg = cnt+1 = ndistinct+1.
__global__ __launch_bounds__(256) void gcn_aggregate(
    const unsigned* __restrict__ bitmap, const _Float16* __restrict__ Y,
    const float* __restrict__ bias, float* __restrict__ out) {
  __shared__ unsigned short list[LISTCAP];
  __shared__ int cnt;
  const int node = blockIdx.x;
  const int tid  = threadIdx.x;
  if (tid == 0) cnt = 0;
  __syncthreads();

  unsigned w = bitmap[(size_t)node * WPR + tid];
  while (w) {
    int bit = __ffs(w) - 1;
    w &= w - 1;
    int pos = atomicAdd(&cnt, 1);
    if (pos < LISTCAP) list[pos] = (unsigned short)(tid * 32 + bit);
  }
  __syncthreads();

  const int n = min(cnt, LISTCAP);
  float a0 = (float)Y[(size_t)node * DFEAT + tid];   // +I self term
  float a1 = 0.f, a2 = 0.f, a3 = 0.f;
  int k = 0;
  for (; k + 4 <= n; k += 4) {
    int j0 = list[k], j1 = list[k + 1], j2 = list[k + 2], j3 = list[k + 3];
    a0 += (float)Y[(size_t)j0 * DFEAT + tid];
    a1 += (float)Y[(size_t)j1 * DFEAT + tid];
    a2 += (float)Y[(size_t)j2 * DFEAT + tid];
    a3 += (float)Y[(size_t)j3 * DFEAT + tid];
  }
  for (; k < n; ++k) a0 += (float)Y[(size_t)list[k] * DFEAT + tid];

  out[(size_t)node * DFEAT + tid] =
      (a0 + a1 + a2 + a3) / (float)(n + 1) + bias[tid];
}

extern "C" void kernel_launch(void* const* d_in, const int* in_sizes, int n_in,
                              void* d_out, int out_size, void* d_ws, size_t ws_size,
                              hipStream_t stream) {
  const float* x  = (const float*)d_in[0];
  const int*   ei = (const int*)d_in[1];
  const float* W  = (const float*)d_in[2];
  const float* b  = (const float*)d_in[3];
  float* out = (float*)d_out;
  const int E = in_sizes[1] / 2;

  // workspace layout (256B-aligned)
  char* p = (char*)d_ws;
  size_t off = 0;
  auto take = [&](size_t bytes) { char* r = p + off; off = (off + bytes + 255) & ~(size_t)255; return r; };
  unsigned* bitmap = (unsigned*) take((size_t)NNODES * WPR * 4);        // 8 MB
  _Float16* Wh     = (_Float16*) take((size_t)DFEAT * DFEAT * 2);       // 128 KB
  _Float16* Wl     = (_Float16*) take((size_t)DFEAT * DFEAT * 2);       // 128 KB
  _Float16* Y      = (_Float16*) take((size_t)NNODES * DFEAT * 2);      // 4 MB

  hipMemsetAsync(bitmap, 0, (size_t)NNODES * WPR * 4, stream);

  const int nbs = (E + 255) / 256;                 // 1024 scatter blocks
  const int nbw = (DFEAT * DFEAT / 4 + 255) / 256; // 64 W-convert blocks
  gcn_scatter_wconv<<<nbs + nbw, 256, 0, stream>>>(ei, E, bitmap, W, Wh, Wl);

  gcn_gemm<<<dim3(NNODES / 64, DFEAT / 64), 256, 0, stream>>>(x, Wh, Wl, Y);

  gcn_aggregate<<<NNODES, 256, 0, stream>>>(bitmap, Y, b, out);
}